// Round 5
// baseline (189.428 us; speedup 1.0000x reference)
//
#include <hip/hip_runtime.h>

typedef __fp16 h2 __attribute__((ext_vector_type(2)));

constexpr int VIEWS = 360;
constexpr int IMGSZ = 512;
constexpr int WCHUNK = 64;    // w per block
constexpr int KH = 104;       // h per LDS chunk (fewer chunks than R0's 64)
constexpr int NPH = 8;        // h-phases (waves per block), 512 threads
constexpr int PITCH = 128;    // dwords per LDS row -> shift-only addressing
constexpr int NXF4 = 32;      // 16B groups per row (PITCH/4), power of two
constexpr int MAXNY = 127;    // max staged rows: ceil(sqrt(63^2+103^2))+6
constexpr int LDSDW = PITCH * MAXNY;  // 16256 dw = 65024 B -> 2 blocks/CU
constexpr int PW = 704;       // padded width (dwords per row)
constexpr int PH = 705;       // padded height
constexpr int PAD = 68;       // overhang bound: 63*|c| + slop(<=5) < 68

// Async global->LDS 16B copy. LDS dest = wave-uniform base + lane*16;
// global src is per-lane.
#define ASYNC_CP16(SRC, DST)                                              \
    __builtin_amdgcn_global_load_lds(                                     \
        (const __attribute__((address_space(1))) unsigned*)(SRC),         \
        (__attribute__((address_space(3))) unsigned*)(DST), 16, 0, 0)

// ---------- pad kernel: zero-padded, BATCH-PACKED f16 texels ---------------
// padq[py][px] = (f16 img_b0[py-PAD][px-PAD], f16 img_b1[py-PAD][px-PAD])
__global__ __launch_bounds__(256) void pad_kernel(const float* __restrict__ x,
                                                  unsigned* __restrict__ padq) {
    constexpr int PW4 = PW / 4;              // 176 groups per row
    constexpr int total = PH * PW4;          // 124080 groups
    int idx = blockIdx.x * 256 + threadIdx.x;
    if (idx >= total) return;
    int py = idx / PW4;
    int px4 = idx - py * PW4;
    int gx = px4 * 4 - PAD;                  // multiple of 4
    int gy = py - PAD;
    const float* img0 = x;
    const float* img1 = x + (size_t)IMGSZ * IMGSZ;
    float4 a = make_float4(0.f, 0.f, 0.f, 0.f);
    float4 bq = a;
    if ((unsigned)gy < (unsigned)IMGSZ && (unsigned)gx < (unsigned)IMGSZ) {
        size_t off = (size_t)gy * IMGSZ + gx;    // gx%4==0 -> all-in/all-out
        a  = *(const float4*)(img0 + off);
        bq = *(const float4*)(img1 + off);
    }
    uint4 d;
    d.x = __builtin_bit_cast(unsigned, __builtin_amdgcn_cvt_pkrtz(a.x, bq.x));
    d.y = __builtin_bit_cast(unsigned, __builtin_amdgcn_cvt_pkrtz(a.y, bq.y));
    d.z = __builtin_bit_cast(unsigned, __builtin_amdgcn_cvt_pkrtz(a.z, bq.z));
    d.w = __builtin_bit_cast(unsigned, __builtin_amdgcn_cvt_pkrtz(a.w, bq.w));
    *(uint4*)&padq[(size_t)idx * 4] = d;
}

// ---------- main kernel: 512 thr, 8 h-phases, KH=104, shift addressing ----
__global__ __launch_bounds__(512) void fp_kernel(const unsigned* __restrict__ padq,
                                                 float* __restrict__ out) {
    __shared__ __align__(16) unsigned tileU[LDSDW];   // 65024 B

    int blk = blockIdx.x;          // 2880 = VIEWS * 8
    int wc = blk & 7;
    int v = blk >> 3;

    int tid = threadIdx.x;
    int lane = tid & 63;
    int p = tid >> 6;              // h phase 0..7
    int w = wc * WCHUNK + lane;

    double ang = -3.14159265358979323846 * (double)(v + 1) / (double)VIEWS
                 - 3.14159265358979323846;
    float c = (float)cos(ang);
    float s = (float)sin(ang);

    float xw = (float)w + 0.5f - 256.0f;
    float cxw = fmaf(c, xw, 255.5f);
    float sxw = fmaf(s, xw, 255.5f);

    // Per-thread valid-h interval (identical to validated rounds 0-1).
    float lo = -1e30f, hi = 1e30f;
    {
        float coef = -s, base = cxw;
        if (fabsf(coef) > 1e-6f) {
            float a = (-1.0f - base) / coef;
            float bq = (512.0f - base) / coef;
            lo = fmaxf(lo, fminf(a, bq));
            hi = fminf(hi, fmaxf(a, bq));
        } else if (!(base > -1.0f && base < 512.0f)) {
            lo = 1e30f; hi = -1e30f;
        }
    }
    {
        float coef = c, base = sxw;
        if (fabsf(coef) > 1e-6f) {
            float a = (-1.0f - base) / coef;
            float bq = (512.0f - base) / coef;
            lo = fmaxf(lo, fminf(a, bq));
            hi = fminf(hi, fmaxf(a, bq));
        } else if (!(base > -1.0f && base < 512.0f)) {
            lo = 1e30f; hi = -1e30f;
        }
    }
    float h0f = fminf(fmaxf(floorf(lo + 255.5f) - 1.0f, 0.0f), 512.0f);
    float h1f = fminf(fmaxf(ceilf(hi + 255.5f) + 1.0f, -1.0f), 511.0f);
    int h0 = (int)h0f;
    int h1 = (int)h1f;

    // Wave-level bounds; identical lane->w map in all 8 waves -> same result.
    int bh0 = h0, bh1 = h1;
    #pragma unroll
    for (int m = 1; m < 64; m <<= 1) {
        bh0 = min(bh0, __shfl_xor(bh0, m, 64));
        bh1 = max(bh1, __shfl_xor(bh1, m, 64));
    }

    float xa = (float)(wc * WCHUNK) + 0.5f - 256.0f;
    float xb = xa + 63.0f;
    float cxa = c * xa, cxb = c * xb;
    float sxa = s * xa, sxb = s * xb;
    float xlo_pair = fminf(cxa, cxb);            // hoisted, view-constant
    float ylo_pair = fminf(sxa, sxb);
    float yhi_pair = fmaxf(sxa, sxb);

    float acc0 = 0.0f, acc1 = 0.0f;
    float step8x = -8.0f * s;
    float step8y = 8.0f * c;

    // Incremental bbox: corners shift linearly by KH per full chunk.
    float ixmn = 0.f, iymn = 0.f, iymx = 0.f;
    bool have = false;

    for (int hc = bh0; hc <= bh1; hc += KH) {
        int hend = min(hc + KH - 1, bh1);

        if (!have || hend != hc + KH - 1) {
            float ha = (float)hc - 255.5f;
            float hb = (float)hend - 255.5f;
            float sha = s * ha, shb = s * hb;
            float cha = c * ha, chb = c * hb;
            ixmn = xlo_pair - fmaxf(sha, shb) + 255.5f;
            iymn = ylo_pair + fminf(cha, chb) + 255.5f;
            iymx = yhi_pair + fmaxf(cha, chb) + 255.5f;
        }
        have = true;

        int x_lo4 = ((int)floorf(ixmn) - 1) & ~3;
        int y_lo = (int)floorf(iymn) - 1;
        int NY = min((int)floorf(iymx) + 3 - y_lo, MAXNY);
        int total4 = NY << 5;              // NY * 32 groups
        int nit = (total4 + 511) >> 9;     // <= 8

        // advance bbox for the next (full) chunk; recomputed if partial
        ixmn -= s * (float)KH;
        iymn += c * (float)KH;
        iymx += c * (float)KH;

        __syncthreads();

        // Async staging; shift-only addressing (no division). Partial tail
        // wave uses the predicated manual path.
        {
            const unsigned* pb = padq + (y_lo + PAD) * PW + (x_lo4 + PAD);
            for (int k = 0; k < nit; ++k) {
                int i = (k << 9) + tid;
                if (((k << 9) + (p << 6) + 63) < total4) {
                    int ry = i >> 5;
                    ASYNC_CP16(pb + ((i & 31) << 2) + ry * PW, &tileU[i << 2]);
                } else if (i < total4) {
                    int ry = i >> 5;
                    uint4 val = *(const uint4*)(pb + ((i & 31) << 2) + ry * PW);
                    *(uint4*)&tileU[i << 2] = val;
                }
            }
        }
        asm volatile("s_waitcnt vmcnt(0)" ::: "memory");
        __syncthreads();

        // Gather: wave p handles h = hc+p, +8, ... (<=13 iters/chunk).
        float hh0 = (float)(hc + p) - 255.5f;
        float ixr = fmaf(-s, hh0, cxw) - (float)x_lo4;
        float iyr = fmaf(c, hh0, sxw) - (float)y_lo;
        h2 accp0 = (h2)0.0f;
        h2 accp1 = (h2)0.0f;
        int parity = 0;
        #pragma unroll 8
        for (int h = hc + p; h <= hend; h += 8) {
            float fx = floorf(ixr);
            float fy = floorf(iyr);
            int lx = (int)fx;
            int ly = (int)fy;
            float wx1 = ixr - fx;
            float wy1 = iyr - fy;
            h2 wxs = __builtin_amdgcn_cvt_pkrtz(wx1, wx1);
            h2 wys = __builtin_amdgcn_cvt_pkrtz(wy1, wy1);
            const unsigned* pt = tileU + ((ly << 7) + lx);
            h2 t00 = __builtin_bit_cast(h2, pt[0]);
            h2 t01 = __builtin_bit_cast(h2, pt[1]);
            h2 t10 = __builtin_bit_cast(h2, pt[PITCH]);
            h2 t11 = __builtin_bit_cast(h2, pt[PITCH + 1]);
            h2 r0 = t00 + (t01 - t00) * wxs;
            h2 r1 = t10 + (t11 - t10) * wxs;
            h2 contrib = r0 + (r1 - r0) * wys;
            if (parity) accp1 += contrib; else accp0 += contrib;
            parity ^= 1;
            ixr += step8x;
            iyr += step8y;
        }
        acc0 += (float)accp0.x + (float)accp1.x;
        acc1 += (float)accp0.y + (float)accp1.y;
    }

    // Reduce the 8 phase partials for both batches, reusing the tile.
    __syncthreads();
    tileU[(p << 6) + lane] = __float_as_uint(acc0);
    tileU[512 + (p << 6) + lane] = __float_as_uint(acc1);
    __syncthreads();
    if (p < 2) {                 // wave 0 -> batch 0, wave 1 -> batch 1
        const unsigned* base = tileU + (p << 9);
        float r = 0.0f;
        #pragma unroll
        for (int q = 0; q < 8; ++q) r += __uint_as_float(base[(q << 6) + lane]);
        size_t o = (size_t)w * VIEWS + v;
        out[o + (size_t)p * IMGSZ * VIEWS] = r * 0.5f;
    }
}

extern "C" void kernel_launch(void* const* d_in, const int* in_sizes, int n_in,
                              void* d_out, int out_size, void* d_ws, size_t ws_size,
                              hipStream_t stream) {
    const float* x = (const float*)d_in[0];
    float* out = (float*)d_out;
    unsigned* padq = (unsigned*)d_ws;   // PH*PW*4 = 1,985,280 bytes

    constexpr int padTotal = PH * (PW / 4);          // 124080 groups
    pad_kernel<<<(padTotal + 255) / 256, 256, 0, stream>>>(x, padq);

    int nblocks = VIEWS * (IMGSZ / WCHUNK);          // 2880
    fp_kernel<<<nblocks, 512, 0, stream>>>(padq, out);
}

// Round 6
// 152.634 us; speedup vs baseline: 1.2411x; 1.2411x over previous
//
#include <hip/hip_runtime.h>

typedef __fp16 h2 __attribute__((ext_vector_type(2)));

constexpr int VIEWS = 360;
constexpr int IMGSZ = 512;
constexpr int WCHUNK = 64;   // w per block
constexpr int KH = 64;       // h per LDS chunk
constexpr int PITCH = 101;   // ODD pitch: vertical views hit all 32 banks (5*l mod 32)
constexpr int MAXNY = 94;    // max staged rows (R0-validated geometry)
constexpr int LDSDW = PITCH * MAXNY;   // 9494 dw = 37976 B -> 4 blocks/CU
constexpr int PW = 712;      // padded width (dword positions per row)
constexpr int PH = 704;      // padded height
constexpr int PAD = 96;
constexpr int RJOBS = 96;    // padded row-job space (>= MAXNY)
constexpr int KJOBS = 25;    // 16B groups per row (100 dwords)
constexpr int NIT = (RJOBS * KJOBS + 255) / 256;   // 10

// ---------- pad kernel: zero-padded, BATCH-PACKED f16 texels ---------------
// padq[py][px] = (f16 img_b0[py-PAD][px-PAD], f16 img_b1[py-PAD][px-PAD])
__global__ __launch_bounds__(256) void pad_kernel(const float* __restrict__ x,
                                                  unsigned* __restrict__ padq) {
    constexpr int PW4 = PW / 4;              // 178 groups per row
    constexpr int total = PH * PW4;          // 125312 groups
    int idx = blockIdx.x * 256 + threadIdx.x;
    if (idx >= total) return;
    int py = idx / PW4;
    int px4 = idx - py * PW4;
    int gx = px4 * 4 - PAD;                  // multiple of 4
    int gy = py - PAD;
    const float* img0 = x;
    const float* img1 = x + (size_t)IMGSZ * IMGSZ;
    float4 a = make_float4(0.f, 0.f, 0.f, 0.f);
    float4 bq = a;
    if ((unsigned)gy < (unsigned)IMGSZ && (unsigned)gx < (unsigned)IMGSZ) {
        size_t off = (size_t)gy * IMGSZ + gx;    // gx%4==0 -> all-in/all-out
        a  = *(const float4*)(img0 + off);
        bq = *(const float4*)(img1 + off);
    }
    uint4 d;
    d.x = __builtin_bit_cast(unsigned, __builtin_amdgcn_cvt_pkrtz(a.x, bq.x));
    d.y = __builtin_bit_cast(unsigned, __builtin_amdgcn_cvt_pkrtz(a.y, bq.y));
    d.z = __builtin_bit_cast(unsigned, __builtin_amdgcn_cvt_pkrtz(a.z, bq.z));
    d.w = __builtin_bit_cast(unsigned, __builtin_amdgcn_cvt_pkrtz(a.w, bq.w));
    *(uint4*)&padq[(size_t)idx * 4] = d;
}

// ---------- main kernel: R0 skeleton + ODD pitch + row-wise staging --------
__global__ __launch_bounds__(256, 4) void fp_kernel(const unsigned* __restrict__ padq,
                                                    float* __restrict__ out) {
    __shared__ __align__(16) unsigned tileU[LDSDW];

    int blk = blockIdx.x;          // 2880 = VIEWS * 8
    int wc = blk & 7;
    int v = blk >> 3;

    int tid = threadIdx.x;
    int lane = tid & 63;
    int g = tid >> 6;              // h phase 0..3
    int w = wc * WCHUNK + lane;

    double ang = -3.14159265358979323846 * (double)(v + 1) / (double)VIEWS
                 - 3.14159265358979323846;
    float c = (float)cos(ang);
    float s = (float)sin(ang);

    float xw = (float)w + 0.5f - 256.0f;
    float cxw = fmaf(c, xw, 255.5f);
    float sxw = fmaf(s, xw, 255.5f);

    // Per-thread valid-h interval (identical to validated rounds 0-4).
    float lo = -1e30f, hi = 1e30f;
    {
        float coef = -s, base = cxw;
        if (fabsf(coef) > 1e-6f) {
            float a = (-1.0f - base) / coef;
            float bq = (512.0f - base) / coef;
            lo = fmaxf(lo, fminf(a, bq));
            hi = fminf(hi, fmaxf(a, bq));
        } else if (!(base > -1.0f && base < 512.0f)) {
            lo = 1e30f; hi = -1e30f;
        }
    }
    {
        float coef = c, base = sxw;
        if (fabsf(coef) > 1e-6f) {
            float a = (-1.0f - base) / coef;
            float bq = (512.0f - base) / coef;
            lo = fmaxf(lo, fminf(a, bq));
            hi = fminf(hi, fmaxf(a, bq));
        } else if (!(base > -1.0f && base < 512.0f)) {
            lo = 1e30f; hi = -1e30f;
        }
    }
    float h0f = fminf(fmaxf(floorf(lo + 255.5f) - 1.0f, 0.0f), 512.0f);
    float h1f = fminf(fmaxf(ceilf(hi + 255.5f) + 1.0f, -1.0f), 511.0f);
    int h0 = (int)h0f;
    int h1 = (int)h1f;

    int bh0 = h0, bh1 = h1;
    #pragma unroll
    for (int m = 1; m < 64; m <<= 1) {
        bh0 = min(bh0, __shfl_xor(bh0, m, 64));
        bh1 = max(bh1, __shfl_xor(bh1, m, 64));
    }

    float xa = (float)(wc * WCHUNK) + 0.5f - 256.0f;
    float xb = xa + 63.0f;

    float acc0 = 0.0f, acc1 = 0.0f;
    float step4x = -4.0f * s;
    float step4y = 4.0f * c;

    for (int hc = bh0; hc <= bh1; hc += KH) {
        int hend = min(hc + KH - 1, bh1);

        float ha = (float)hc - 255.5f;
        float hb = (float)hend - 255.5f;
        float ix00 = c * xa - s * ha, ix01 = c * xa - s * hb;
        float ix10 = c * xb - s * ha, ix11 = c * xb - s * hb;
        float iy00 = s * xa + c * ha, iy01 = s * xa + c * hb;
        float iy10 = s * xb + c * ha, iy11 = s * xb + c * hb;
        float ixmn = fminf(fminf(ix00, ix01), fminf(ix10, ix11)) + 255.5f;
        float iymn = fminf(fminf(iy00, iy01), fminf(iy10, iy11)) + 255.5f;
        float iymx = fmaxf(fmaxf(iy00, iy01), fmaxf(iy10, iy11)) + 255.5f;
        int x_lo = (int)floorf(ixmn) - 1;
        int x_lo4 = x_lo & ~3;
        int y_lo = (int)floorf(iymn) - 1;
        int NY = min((int)floorf(iymx) + 3 - y_lo, MAXNY);

        __syncthreads();

        // Row-wise reg-staged copy: job j -> (row r = j mod 96, group k = j/96).
        // Consecutive lanes write consecutive ROWS (addr stride 101 dw, odd)
        // -> LDS writes conflict-free. Clamped duplicates are benign.
        {
            const unsigned* pb = padq + (y_lo + PAD) * PW + (x_lo4 + PAD);
            uint4 vals[NIT];
            #pragma unroll
            for (int it = 0; it < NIT; ++it) {
                int j = min(it * 256 + tid, RJOBS * KJOBS - 1);
                int k = j / RJOBS;             // 0..24 (const magic-div)
                int r = j - k * RJOBS;         // 0..95
                int rr = min(r, NY - 1);
                vals[it] = *(const uint4*)(pb + rr * PW + (k << 2));
            }
            #pragma unroll
            for (int it = 0; it < NIT; ++it) {
                int j = min(it * 256 + tid, RJOBS * KJOBS - 1);
                int k = j / RJOBS;
                int r = j - k * RJOBS;
                int rr = min(r, NY - 1);
                int base = rr * PITCH + (k << 2);
                tileU[base + 0] = vals[it].x;
                tileU[base + 1] = vals[it].y;
                tileU[base + 2] = vals[it].z;
                tileU[base + 3] = vals[it].w;
            }
        }
        __syncthreads();

        // Gather: 2 x ds_read2_b32 per sample; packed-f16 lerp serves both
        // batches at once. Wave g handles h = hc+g, +4, ...
        // In-tile coords are strictly positive -> trunc == floor, v_fract ok.
        float hh0 = (float)(hc + g) - 255.5f;
        float ixr = fmaf(-s, hh0, cxw) - (float)x_lo4;
        float iyr = fmaf(c, hh0, sxw) - (float)y_lo;
        h2 accp0 = (h2)0.0f;
        h2 accp1 = (h2)0.0f;
        int parity = 0;
        #pragma unroll 8
        for (int h = hc + g; h <= hend; h += 4) {
            int lx = (int)ixr;
            int ly = (int)iyr;
            float wx1 = __builtin_amdgcn_fractf(ixr);
            float wy1 = __builtin_amdgcn_fractf(iyr);
            h2 wxs = __builtin_amdgcn_cvt_pkrtz(wx1, wx1);
            h2 wys = __builtin_amdgcn_cvt_pkrtz(wy1, wy1);
            const unsigned* p = tileU + (ly * PITCH + lx);
            h2 t00 = __builtin_bit_cast(h2, p[0]);
            h2 t01 = __builtin_bit_cast(h2, p[1]);
            h2 t10 = __builtin_bit_cast(h2, p[PITCH]);
            h2 t11 = __builtin_bit_cast(h2, p[PITCH + 1]);
            h2 r0 = t00 + (t01 - t00) * wxs;
            h2 r1 = t10 + (t11 - t10) * wxs;
            h2 contrib = r0 + (r1 - r0) * wys;
            if (parity) accp1 += contrib; else accp0 += contrib;
            parity ^= 1;
            ixr += step4x;
            iyr += step4y;
        }
        acc0 += (float)accp0.x + (float)accp1.x;
        acc1 += (float)accp0.y + (float)accp1.y;
    }

    // Reduce the 4 h-phase partials for both batches, reusing the tile.
    __syncthreads();
    tileU[(g << 6) + lane] = __float_as_uint(acc0);
    tileU[256 + (g << 6) + lane] = __float_as_uint(acc1);
    __syncthreads();
    if (g == 0) {
        float r0 = __uint_as_float(tileU[lane]) + __uint_as_float(tileU[64 + lane]) +
                   __uint_as_float(tileU[128 + lane]) + __uint_as_float(tileU[192 + lane]);
        float r1 = __uint_as_float(tileU[256 + lane]) + __uint_as_float(tileU[320 + lane]) +
                   __uint_as_float(tileU[384 + lane]) + __uint_as_float(tileU[448 + lane]);
        size_t o = (size_t)w * VIEWS + v;
        out[o] = r0 * 0.5f;
        out[(size_t)IMGSZ * VIEWS + o] = r1 * 0.5f;
    }
}

extern "C" void kernel_launch(void* const* d_in, const int* in_sizes, int n_in,
                              void* d_out, int out_size, void* d_ws, size_t ws_size,
                              hipStream_t stream) {
    const float* x = (const float*)d_in[0];
    float* out = (float*)d_out;
    unsigned* padq = (unsigned*)d_ws;   // PH*PW*4 = 2,004,992 bytes

    constexpr int padTotal = PH * (PW / 4);          // 125312 groups
    pad_kernel<<<(padTotal + 255) / 256, 256, 0, stream>>>(x, padq);

    int nblocks = VIEWS * (IMGSZ / WCHUNK);          // 2880
    fp_kernel<<<nblocks, 256, 0, stream>>>(padq, out);
}